// Round 1
// baseline (817.365 us; speedup 1.0000x reference)
//
#include <hip/hip_runtime.h>

typedef unsigned short u16;
typedef float f32x4 __attribute__((ext_vector_type(4)));
typedef short bf16x8 __attribute__((ext_vector_type(8)));

#define B_ 4
#define T_ 2048
#define E_ 2048
#define G_ 4
#define QG_ 4
#define D_ 128
#define H_ 16
#define BT_ 8192

__device__ __forceinline__ u16 f2bf(float f) {
  union { float f; unsigned u; } v; v.f = f;
  unsigned r = v.u + 0x7fffu + ((v.u >> 16) & 1u);
  return (u16)(r >> 16);
}
__device__ __forceinline__ float bf2f(u16 b) {
  union { unsigned u; float f; } v; v.u = ((unsigned)b) << 16;
  return v.f;
}

#define GL2LDS(g, l) __builtin_amdgcn_global_load_lds( \
    (const __attribute__((address_space(1))) void*)(g), \
    (__attribute__((address_space(3))) void*)(l), 16, 0, 0)

#define MFMA(a, b, c) __builtin_amdgcn_mfma_f32_16x16x32_bf16((a), (b), (c), 0, 0, 0)

// ---------------- elementwise converters ----------------

__global__ void k_cvt_x(const float4* __restrict__ x, uint2* __restrict__ xb) {
  int i = blockIdx.x * 256 + threadIdx.x;
  float4 v = x[i];
  uint2 o;
  o.x = (unsigned)f2bf(v.x) | ((unsigned)f2bf(v.y) << 16);
  o.y = (unsigned)f2bf(v.z) | ((unsigned)f2bf(v.w) << 16);
  xb[i] = o;
}

// W [R][C] fp32 -> WT [C][R] bf16  (64x64 LDS tile transpose)
__global__ void k_cvt_wT(const float* __restrict__ W, u16* __restrict__ WT,
                         int R, int C) {
  __shared__ float tile[64][65];
  int c0 = blockIdx.x * 64, r0 = blockIdx.y * 64;
  int tid = threadIdx.x;
#pragma unroll
  for (int p = 0; p < 16; ++p) {
    int idx = p * 256 + tid;
    int i = idx >> 6, j = idx & 63;
    tile[i][j] = W[(size_t)(r0 + i) * C + c0 + j];
  }
  __syncthreads();
#pragma unroll
  for (int p = 0; p < 16; ++p) {
    int idx = p * 256 + tid;
    int i = idx >> 6, j = idx & 63;
    WT[(size_t)(c0 + i) * R + r0 + j] = f2bf(tile[j][i]);
  }
}

__global__ void k_tables(float* __restrict__ ct, float* __restrict__ st) {
  int i = blockIdx.x * 256 + threadIdx.x;  // T_*64
  int t = i >> 6, j = i & 63;
  float freq = powf(10000.f, -(float)j / 64.f);
  float ang = (float)t * freq;
  ct[i] = cosf(ang);
  st[i] = sinf(ang);
}

// ---------------- GEMM: C[M,N] = A[M,K] * B[K,N], B given transposed [N,K] ----
// m97 structure: 128x128 tile, BK=32, 4 waves, global_load_lds w16.

template <int OUTBF>
__global__ __launch_bounds__(256) void k_gemm_bt(
    const u16* __restrict__ A, const u16* __restrict__ BT,
    void* __restrict__ C, int M, int N, int K) {
  __shared__ u16 As[128 * 32];
  __shared__ u16 Bs[128 * 32];
  const int tid = threadIdx.x;
  const int wave = tid >> 6;
  const int lane = tid & 63;
  const int lo = lane & 15, hi = lane >> 4;
  const int m0 = blockIdx.y * 128, n0 = blockIdx.x * 128;
  const int wm = (wave >> 1) * 64, wn = (wave & 1) * 64;
  f32x4 acc[4][4] = {};

  for (int k0 = 0; k0 < K; k0 += 32) {
#pragma unroll
    for (int r = 0; r < 2; ++r) {
      int c = r * 256 + tid;
      int row = c >> 2, kc = c & 3;
      GL2LDS(A + (size_t)(m0 + row) * K + k0 + kc * 8,
             &As[(r * 256 + wave * 64) * 8]);
      GL2LDS(BT + (size_t)(n0 + row) * K + k0 + kc * 8,
             &Bs[(r * 256 + wave * 64) * 8]);
    }
    __syncthreads();
    bf16x8 af[4], bfr[4];
#pragma unroll
    for (int i = 0; i < 4; ++i) {
      af[i]  = *(const bf16x8*)&As[(wm + i * 16 + lo) * 32 + hi * 8];
      bfr[i] = *(const bf16x8*)&Bs[(wn + i * 16 + lo) * 32 + hi * 8];
    }
#pragma unroll
    for (int i = 0; i < 4; ++i)
#pragma unroll
      for (int j = 0; j < 4; ++j)
        acc[i][j] = MFMA(af[i], bfr[j], acc[i][j]);
    __syncthreads();
  }
#pragma unroll
  for (int i = 0; i < 4; ++i)
#pragma unroll
    for (int j = 0; j < 4; ++j)
#pragma unroll
      for (int r = 0; r < 4; ++r) {
        int row = m0 + wm + i * 16 + hi * 4 + r;
        int col = n0 + wn + j * 16 + lo;
        if (OUTBF) ((u16*)C)[(size_t)row * N + col] = f2bf(acc[i][j][r]);
        else       ((float*)C)[(size_t)row * N + col] = acc[i][j][r];
      }
}

// ---------------- RoPE + layout [bt, h*D] -> [b, h, t, D] ----------------

__global__ void k_rope(const u16* __restrict__ src, u16* __restrict__ dst,
                       const float* __restrict__ ct, const float* __restrict__ st,
                       int hbits) {
  int i = blockIdx.x * 256 + threadIdx.x;  // BT_ * heads * 64
  int j = i & 63;
  int h = (i >> 6) & ((1 << hbits) - 1);
  int bt = i >> (6 + hbits);
  int t = bt & (T_ - 1), b = bt >> 11;
  size_t srow = ((size_t)bt << (7 + hbits)) + ((size_t)h << 7);
  float x1 = bf2f(src[srow + j]);
  float x2 = bf2f(src[srow + 64 + j]);
  float c = ct[t * 64 + j], s = st[t * 64 + j];
  size_t drow = (((size_t)((b << hbits) + h)) * T_ + t) << 7;
  dst[drow + j]      = f2bf(x1 * c - x2 * s);
  dst[drow + 64 + j] = f2bf(x1 * s + x2 * c);
}

// v [bt, G*D] bf16 -> vT [b, g, d, t] bf16 (64x64 LDS transpose)
__global__ void k_vtrans(const u16* __restrict__ vg, u16* __restrict__ vT) {
  __shared__ u16 tile[64][65];
  int t0 = blockIdx.x * 64;
  int d0 = blockIdx.y * 64;
  int bg = blockIdx.z;
  int g = bg & (G_ - 1), b = bg >> 2;
  int tid = threadIdx.x;
#pragma unroll
  for (int p = 0; p < 16; ++p) {
    int idx = p * 256 + tid;
    int i = idx >> 6, j = idx & 63;
    tile[i][j] = vg[(size_t)(b * T_ + t0 + i) * (G_ * D_) + g * D_ + d0 + j];
  }
  __syncthreads();
#pragma unroll
  for (int p = 0; p < 16; ++p) {
    int idx = p * 256 + tid;
    int i = idx >> 6, j = idx & 63;  // i: d-local, j: t-local
    vT[((size_t)bg * D_ + d0 + i) * T_ + t0 + j] = tile[j][i];
  }
}

// ---------------- causal flash attention ----------------
// grid: (T_/128, B_*H_); 4 waves; wave owns 32 q rows; KV tiles of 32.

__global__ __launch_bounds__(256) void k_attn(
    const u16* __restrict__ qh, const u16* __restrict__ kh,
    const u16* __restrict__ vT, u16* __restrict__ ab) {
  __shared__ u16 Ks[32 * 128];
  __shared__ u16 Vs[128 * 32];
  __shared__ u16 Ps[4][32 * 32];
  const int tid = threadIdx.x;
  const int wave = tid >> 6;
  const int lane = tid & 63;
  const int lo = lane & 15, hi = lane >> 4;
  const int bh = blockIdx.y;
  const int b = bh >> 4, h = bh & 15;
  const int g = h >> 2;
  const int i0 = blockIdx.x * 128;
  const int wq = wave * 32;
  const int qg0 = i0 + wq;  // wave's first global q row

  const u16* Qbase = qh + ((size_t)bh * T_ + i0 + wq) * D_;
  bf16x8 aq[2][4];
#pragma unroll
  for (int mi = 0; mi < 2; ++mi)
#pragma unroll
    for (int ks = 0; ks < 4; ++ks)
      aq[mi][ks] = *(const bf16x8*)(Qbase + (size_t)(mi * 16 + lo) * D_ + ks * 32 + hi * 8);

  f32x4 acc_o[2][8] = {};
  float mrun[2][4], lrun[2][4];
#pragma unroll
  for (int mi = 0; mi < 2; ++mi)
#pragma unroll
    for (int r = 0; r < 4; ++r) { mrun[mi][r] = -1e30f; lrun[mi][r] = 0.f; }

  const u16* Kbase = kh + (size_t)(b * G_ + g) * T_ * D_;
  const u16* Vbase = vT + (size_t)(b * G_ + g) * D_ * T_;

  const int nt = (i0 + 128) >> 5;
  for (int ti = 0; ti < nt; ++ti) {
    const int s0 = ti << 5;
#pragma unroll
    for (int r = 0; r < 2; ++r) {
      int c = r * 256 + tid;
      GL2LDS(Kbase + (size_t)(s0 + (c >> 4)) * D_ + (c & 15) * 8,
             &Ks[(r * 256 + wave * 64) * 8]);
      GL2LDS(Vbase + (size_t)(c >> 2) * T_ + s0 + (c & 3) * 8,
             &Vs[(r * 256 + wave * 64) * 8]);
    }
    __syncthreads();
    if (s0 <= qg0 + 31) {
      f32x4 sa[2][2] = {};
#pragma unroll
      for (int ks = 0; ks < 4; ++ks) {
        bf16x8 bk0 = *(const bf16x8*)&Ks[(lo) * 128 + ks * 32 + hi * 8];
        bf16x8 bk1 = *(const bf16x8*)&Ks[(16 + lo) * 128 + ks * 32 + hi * 8];
#pragma unroll
        for (int mi = 0; mi < 2; ++mi) {
          sa[mi][0] = MFMA(aq[mi][ks], bk0, sa[mi][0]);
          sa[mi][1] = MFMA(aq[mi][ks], bk1, sa[mi][1]);
        }
      }
      const float scale = 0.088388347648318447f;
      const bool needmask = (s0 + 31 > qg0);
#pragma unroll
      for (int mi = 0; mi < 2; ++mi)
#pragma unroll
        for (int nj = 0; nj < 2; ++nj)
#pragma unroll
          for (int r = 0; r < 4; ++r) {
            float sv = sa[mi][nj][r] * scale;
            if (needmask) {
              int q = qg0 + mi * 16 + hi * 4 + r;
              int s = s0 + nj * 16 + lo;
              if (s > q) sv = -1e30f;
            }
            sa[mi][nj][r] = sv;
          }
      float alpha[2][4];
#pragma unroll
      for (int mi = 0; mi < 2; ++mi)
#pragma unroll
        for (int r = 0; r < 4; ++r) {
          float pm = fmaxf(sa[mi][0][r], sa[mi][1][r]);
#pragma unroll
          for (int msk = 1; msk < 16; msk <<= 1)
            pm = fmaxf(pm, __shfl_xor(pm, msk));
          float mo = mrun[mi][r];
          float mn = fmaxf(mo, pm);
          alpha[mi][r] = __expf(mo - mn);
          mrun[mi][r] = mn;
        }
      float rs[2][4];
#pragma unroll
      for (int mi = 0; mi < 2; ++mi)
#pragma unroll
        for (int r = 0; r < 4; ++r) {
          float mn = mrun[mi][r];
          float p0 = __expf(sa[mi][0][r] - mn);
          float p1 = __expf(sa[mi][1][r] - mn);
          Ps[wave][(mi * 16 + hi * 4 + r) * 32 + lo]      = f2bf(p0);
          Ps[wave][(mi * 16 + hi * 4 + r) * 32 + 16 + lo] = f2bf(p1);
          float s2 = p0 + p1;
#pragma unroll
          for (int msk = 1; msk < 16; msk <<= 1)
            s2 += __shfl_xor(s2, msk);
          rs[mi][r] = s2;
        }
#pragma unroll
      for (int mi = 0; mi < 2; ++mi)
#pragma unroll
        for (int r = 0; r < 4; ++r)
          lrun[mi][r] = lrun[mi][r] * alpha[mi][r] + rs[mi][r];
#pragma unroll
      for (int mi = 0; mi < 2; ++mi)
#pragma unroll
        for (int dt = 0; dt < 8; ++dt)
#pragma unroll
          for (int r = 0; r < 4; ++r)
            acc_o[mi][dt][r] *= alpha[mi][r];
      bf16x8 ap0 = *(const bf16x8*)&Ps[wave][(lo) * 32 + hi * 8];
      bf16x8 ap1 = *(const bf16x8*)&Ps[wave][(16 + lo) * 32 + hi * 8];
#pragma unroll
      for (int dt = 0; dt < 8; ++dt) {
        bf16x8 bv = *(const bf16x8*)&Vs[(dt * 16 + lo) * 32 + hi * 8];
        acc_o[0][dt] = MFMA(ap0, bv, acc_o[0][dt]);
        acc_o[1][dt] = MFMA(ap1, bv, acc_o[1][dt]);
      }
    }
    __syncthreads();
  }
#pragma unroll
  for (int mi = 0; mi < 2; ++mi)
#pragma unroll
    for (int r = 0; r < 4; ++r) {
      float iv = 1.f / lrun[mi][r];
      int q = qg0 + mi * 16 + hi * 4 + r;
      size_t rowbase = ((size_t)(b * T_ + q)) * (H_ * D_) + (size_t)h * D_;
#pragma unroll
      for (int dt = 0; dt < 8; ++dt)
        ab[rowbase + dt * 16 + lo] = f2bf(acc_o[mi][dt][r] * iv);
    }
}

// ---------------- launch ----------------

extern "C" void kernel_launch(void* const* d_in, const int* in_sizes, int n_in,
                              void* d_out, int out_size, void* d_ws, size_t ws_size,
                              hipStream_t stream) {
  const float* x  = (const float*)d_in[0];
  const float* Wq = (const float*)d_in[1];
  const float* Wk = (const float*)d_in[2];
  const float* Wv = (const float*)d_in[3];
  const float* Wo = (const float*)d_in[4];

  char* base = (char*)d_ws;
  size_t off = 0;
  auto nxt = [&](size_t bytes) {
    char* r = base + off;
    off += (bytes + 255) & ~(size_t)255;
    return r;
  };
  u16*   xb  = (u16*)nxt((size_t)BT_ * E_ * 2);
  u16*   wqT = (u16*)nxt((size_t)E_ * E_ * 2);          // [2048][2048]
  u16*   wkT = (u16*)nxt((size_t)(G_ * D_) * E_ * 2);   // [512][2048]
  u16*   wvT = (u16*)nxt((size_t)(G_ * D_) * E_ * 2);
  u16*   woT = (u16*)nxt((size_t)E_ * E_ * 2);
  float* ct  = (float*)nxt((size_t)T_ * 64 * 4);
  float* st  = (float*)nxt((size_t)T_ * 64 * 4);
  u16*   qg  = (u16*)nxt((size_t)BT_ * E_ * 2);
  u16*   kg  = (u16*)nxt((size_t)BT_ * (G_ * D_) * 2);
  u16*   vg  = (u16*)nxt((size_t)BT_ * (G_ * D_) * 2);
  u16*   vTb = (u16*)nxt((size_t)BT_ * (G_ * D_) * 2);
  // safe aliases (strict producer/consumer ordering):
  u16* qhb = xb;   // xb last read by v-GEMM; qhb written after
  u16* khb = wqT;  // wqT last read by q-GEMM; khb written after
  u16* ab  = qg;   // qg last read by k_rope(q); ab written by k_attn after

  k_cvt_x<<<BT_ * E_ / 4 / 256, 256, 0, stream>>>((const float4*)x, (uint2*)xb);
  k_cvt_wT<<<dim3(E_ / 64, E_ / 64), 256, 0, stream>>>(Wq, wqT, E_, E_);
  k_cvt_wT<<<dim3((G_ * D_) / 64, E_ / 64), 256, 0, stream>>>(Wk, wkT, E_, G_ * D_);
  k_cvt_wT<<<dim3((G_ * D_) / 64, E_ / 64), 256, 0, stream>>>(Wv, wvT, E_, G_ * D_);
  k_cvt_wT<<<dim3(E_ / 64, E_ / 64), 256, 0, stream>>>(Wo, woT, E_, E_);
  k_tables<<<T_ * 64 / 256, 256, 0, stream>>>(ct, st);

  k_gemm_bt<1><<<dim3(E_ / 128, BT_ / 128), 256, 0, stream>>>(xb, wqT, qg, BT_, E_, E_);
  k_gemm_bt<1><<<dim3((G_ * D_) / 128, BT_ / 128), 256, 0, stream>>>(xb, wkT, kg, BT_, G_ * D_, E_);
  k_gemm_bt<1><<<dim3((G_ * D_) / 128, BT_ / 128), 256, 0, stream>>>(xb, wvT, vg, BT_, G_ * D_, E_);

  k_rope<<<BT_ * H_ * 64 / 256, 256, 0, stream>>>(qg, qhb, ct, st, 4);
  k_rope<<<BT_ * G_ * 64 / 256, 256, 0, stream>>>(kg, khb, ct, st, 2);
  k_vtrans<<<dim3(T_ / 64, D_ / 64, B_ * G_), 256, 0, stream>>>(vg, vTb);

  k_attn<<<dim3(T_ / 128, B_ * H_), 256, 0, stream>>>(qhb, khb, vTb, ab);

  k_gemm_bt<0><<<dim3(E_ / 128, BT_ / 128), 256, 0, stream>>>(ab, woT, d_out, BT_, E_, E_);
}

// Round 2
// 812.525 us; speedup vs baseline: 1.0060x; 1.0060x over previous
//
#include <hip/hip_runtime.h>

typedef unsigned short u16;
typedef float f32x4 __attribute__((ext_vector_type(4)));
typedef short bf16x8 __attribute__((ext_vector_type(8)));

#define B_ 4
#define T_ 2048
#define E_ 2048
#define G_ 4
#define QG_ 4
#define D_ 128
#define H_ 16
#define BT_ 8192

__device__ __forceinline__ u16 f2bf(float f) {
  union { float f; unsigned u; } v; v.f = f;
  unsigned r = v.u + 0x7fffu + ((v.u >> 16) & 1u);
  return (u16)(r >> 16);
}
__device__ __forceinline__ float bf2f(u16 b) {
  union { unsigned u; float f; } v; v.u = ((unsigned)b) << 16;
  return v.f;
}

#define GL2LDS(g, l) __builtin_amdgcn_global_load_lds( \
    (const __attribute__((address_space(1))) void*)(g), \
    (__attribute__((address_space(3))) void*)(l), 16, 0, 0)

#define MFMA(a, b, c) __builtin_amdgcn_mfma_f32_16x16x32_bf16((a), (b), (c), 0, 0, 0)

// ---------------- elementwise converters ----------------

__global__ void k_cvt_x(const float4* __restrict__ x, uint2* __restrict__ xb) {
  int i = blockIdx.x * 256 + threadIdx.x;
  float4 v = x[i];
  uint2 o;
  o.x = (unsigned)f2bf(v.x) | ((unsigned)f2bf(v.y) << 16);
  o.y = (unsigned)f2bf(v.z) | ((unsigned)f2bf(v.w) << 16);
  xb[i] = o;
}

// W [R][C] fp32 -> WT [C][R] bf16  (64x64 LDS tile transpose)
__global__ void k_cvt_wT(const float* __restrict__ W, u16* __restrict__ WT,
                         int R, int C) {
  __shared__ float tile[64][65];
  int c0 = blockIdx.x * 64, r0 = blockIdx.y * 64;
  int tid = threadIdx.x;
#pragma unroll
  for (int p = 0; p < 16; ++p) {
    int idx = p * 256 + tid;
    int i = idx >> 6, j = idx & 63;
    tile[i][j] = W[(size_t)(r0 + i) * C + c0 + j];
  }
  __syncthreads();
#pragma unroll
  for (int p = 0; p < 16; ++p) {
    int idx = p * 256 + tid;
    int i = idx >> 6, j = idx & 63;
    WT[(size_t)(c0 + i) * R + r0 + j] = f2bf(tile[j][i]);
  }
}

__global__ void k_tables(float* __restrict__ ct, float* __restrict__ st) {
  int i = blockIdx.x * 256 + threadIdx.x;  // T_*64
  int t = i >> 6, j = i & 63;
  float freq = powf(10000.f, -(float)j / 64.f);
  float ang = (float)t * freq;
  ct[i] = cosf(ang);
  st[i] = sinf(ang);
}

// ---------------- GEMM: C[M,N] = A[M,K] * B[K,N], B given transposed [N,K] ----
// m97 structure: 128x128 tile, BK=32, 4 waves, global_load_lds w16.

template <int OUTBF>
__global__ __launch_bounds__(256) void k_gemm_bt(
    const u16* __restrict__ A, const u16* __restrict__ BT,
    void* __restrict__ C, int M, int N, int K) {
  __shared__ u16 As[128 * 32];
  __shared__ u16 Bs[128 * 32];
  const int tid = threadIdx.x;
  const int wave = tid >> 6;
  const int lane = tid & 63;
  const int lo = lane & 15, hi = lane >> 4;
  const int m0 = blockIdx.y * 128, n0 = blockIdx.x * 128;
  const int wm = (wave >> 1) * 64, wn = (wave & 1) * 64;
  f32x4 acc[4][4] = {};

  for (int k0 = 0; k0 < K; k0 += 32) {
#pragma unroll
    for (int r = 0; r < 2; ++r) {
      int c = r * 256 + tid;
      int row = c >> 2, kc = c & 3;
      GL2LDS(A + (size_t)(m0 + row) * K + k0 + kc * 8,
             &As[(r * 256 + wave * 64) * 8]);
      GL2LDS(BT + (size_t)(n0 + row) * K + k0 + kc * 8,
             &Bs[(r * 256 + wave * 64) * 8]);
    }
    __syncthreads();
    bf16x8 af[4], bfr[4];
#pragma unroll
    for (int i = 0; i < 4; ++i) {
      af[i]  = *(const bf16x8*)&As[(wm + i * 16 + lo) * 32 + hi * 8];
      bfr[i] = *(const bf16x8*)&Bs[(wn + i * 16 + lo) * 32 + hi * 8];
    }
#pragma unroll
    for (int i = 0; i < 4; ++i)
#pragma unroll
      for (int j = 0; j < 4; ++j)
        acc[i][j] = MFMA(af[i], bfr[j], acc[i][j]);
    __syncthreads();
  }
#pragma unroll
  for (int i = 0; i < 4; ++i)
#pragma unroll
    for (int j = 0; j < 4; ++j)
#pragma unroll
      for (int r = 0; r < 4; ++r) {
        int row = m0 + wm + i * 16 + hi * 4 + r;
        int col = n0 + wn + j * 16 + lo;
        if (OUTBF) ((u16*)C)[(size_t)row * N + col] = f2bf(acc[i][j][r]);
        else       ((float*)C)[(size_t)row * N + col] = acc[i][j][r];
      }
}

// ---------------- RoPE + layout [bt, h*D] -> [b, h, t, D] ----------------

__global__ void k_rope(const u16* __restrict__ src, u16* __restrict__ dst,
                       const float* __restrict__ ct, const float* __restrict__ st,
                       int hbits) {
  int i = blockIdx.x * 256 + threadIdx.x;  // BT_ * heads * 64
  int j = i & 63;
  int h = (i >> 6) & ((1 << hbits) - 1);
  int bt = i >> (6 + hbits);
  int t = bt & (T_ - 1), b = bt >> 11;
  size_t srow = ((size_t)bt << (7 + hbits)) + ((size_t)h << 7);
  float x1 = bf2f(src[srow + j]);
  float x2 = bf2f(src[srow + 64 + j]);
  float c = ct[t * 64 + j], s = st[t * 64 + j];
  size_t drow = (((size_t)((b << hbits) + h)) * T_ + t) << 7;
  dst[drow + j]      = f2bf(x1 * c - x2 * s);
  dst[drow + 64 + j] = f2bf(x1 * s + x2 * c);
}

// v [bt, G*D] bf16 -> vT [b, g, d, t] bf16 (64x64 LDS transpose)
__global__ void k_vtrans(const u16* __restrict__ vg, u16* __restrict__ vT) {
  __shared__ u16 tile[64][65];
  int t0 = blockIdx.x * 64;
  int d0 = blockIdx.y * 64;
  int bg = blockIdx.z;
  int g = bg & (G_ - 1), b = bg >> 2;
  int tid = threadIdx.x;
#pragma unroll
  for (int p = 0; p < 16; ++p) {
    int idx = p * 256 + tid;
    int i = idx >> 6, j = idx & 63;
    tile[i][j] = vg[(size_t)(b * T_ + t0 + i) * (G_ * D_) + g * D_ + d0 + j];
  }
  __syncthreads();
#pragma unroll
  for (int p = 0; p < 16; ++p) {
    int idx = p * 256 + tid;
    int i = idx >> 6, j = idx & 63;  // i: d-local, j: t-local
    vT[((size_t)bg * D_ + d0 + i) * T_ + t0 + j] = tile[j][i];
  }
}

// ---------------- causal flash attention ----------------
// grid: (T_/128, B_*H_); 4 waves; wave owns 32 q rows; KV tiles of 64,
// double-buffered LDS, XOR-swizzled (pre-swizzled global source for
// global_load_lds per rule #21; same XOR on ds_read side).

__global__ __launch_bounds__(256) void k_attn(
    const u16* __restrict__ qh, const u16* __restrict__ kh,
    const u16* __restrict__ vT, u16* __restrict__ ab) {
  __shared__ u16 Ks[2][64 * 128];   // [s][d], rows 256B, swizzled
  __shared__ u16 Vs[2][128 * 64];   // [d][s], rows 128B, swizzled
  __shared__ u16 Ps[4][32 * 64];    // [q][s], rows 128B, swizzled
  const int tid = threadIdx.x;
  const int wave = tid >> 6;
  const int lane = tid & 63;
  const int lo = lane & 15, hi = lane >> 4;
  const int bh = blockIdx.y;
  const int b = bh >> 4, h = bh & 15;
  const int g = h >> 2;
  const int i0 = blockIdx.x * 128;
  const int qg0 = i0 + wave * 32;  // wave's first global q row

  const u16* Qbase = qh + ((size_t)bh * T_ + qg0) * D_;
  bf16x8 aq[2][4];
#pragma unroll
  for (int mi = 0; mi < 2; ++mi)
#pragma unroll
    for (int ks = 0; ks < 4; ++ks)
      aq[mi][ks] = *(const bf16x8*)(Qbase + (size_t)(mi * 16 + lo) * D_ + ks * 32 + hi * 8);

  f32x4 acc_o[2][8] = {};
  float mrun[2][4], lrun[2][4];
#pragma unroll
  for (int mi = 0; mi < 2; ++mi)
#pragma unroll
    for (int r = 0; r < 4; ++r) { mrun[mi][r] = -1e30f; lrun[mi][r] = 0.f; }

  const u16* Kbase = kh + (size_t)(b * G_ + g) * T_ * D_;
  const u16* Vbase = vT + (size_t)(b * G_ + g) * D_ * T_;

  // stage KV tile at s0 into buffer bi; pre-swizzled global source.
  auto stage = [&](int bi, int s0) {
#pragma unroll
    for (int r = 0; r < 4; ++r) {
      int p = r * 256 + tid;
      {  // K: 64 rows x 16 chunks
        int row = p >> 4, c = p & 15;
        GL2LDS(Kbase + (size_t)(s0 + row) * D_ + ((c ^ (row & 7)) * 8),
               &Ks[bi][(r * 256 + wave * 64) * 8]);
      }
      {  // V: 128 rows x 8 chunks
        int row = p >> 3, c = p & 7;
        GL2LDS(Vbase + (size_t)row * T_ + s0 + ((c ^ (row & 7)) * 8),
               &Vs[bi][(r * 256 + wave * 64) * 8]);
      }
    }
  };

  const int nt = (i0 + 128) >> 6;  // # of 64-wide KV tiles
  stage(0, 0);
  int bufc = 0;
  for (int ti = 0; ti < nt; ++ti) {
    const int s0 = ti << 6;
    __syncthreads();  // drains vmcnt -> tile ti ready; protects buf bufc^1
    if (ti + 1 < nt) stage(bufc ^ 1, (ti + 1) << 6);
    if (s0 <= qg0 + 31) {
      // ---- QK^T: S[2 mi][4 nj] over 64 s cols ----
      f32x4 sa[2][4] = {};
#pragma unroll
      for (int ks = 0; ks < 4; ++ks) {
        bf16x8 bk[4];
#pragma unroll
        for (int nj = 0; nj < 4; ++nj) {
          int row = nj * 16 + lo;
          bk[nj] = *(const bf16x8*)&Ks[bufc][row * 128 + ((ks * 4 + hi) ^ (row & 7)) * 8];
        }
#pragma unroll
        for (int mi = 0; mi < 2; ++mi)
#pragma unroll
          for (int nj = 0; nj < 4; ++nj)
            sa[mi][nj] = MFMA(aq[mi][ks], bk[nj], sa[mi][nj]);
      }
      const float scale = 0.088388347648318447f;
      const bool needmask = (s0 + 63 > qg0);
#pragma unroll
      for (int mi = 0; mi < 2; ++mi)
#pragma unroll
        for (int nj = 0; nj < 4; ++nj)
#pragma unroll
          for (int r = 0; r < 4; ++r) {
            float sv = sa[mi][nj][r] * scale;
            if (needmask) {
              int q = qg0 + mi * 16 + hi * 4 + r;
              int s = s0 + nj * 16 + lo;
              if (s > q) sv = -1e30f;
            }
            sa[mi][nj][r] = sv;
          }
      // ---- online softmax ----
      float alpha[2][4];
#pragma unroll
      for (int mi = 0; mi < 2; ++mi)
#pragma unroll
        for (int r = 0; r < 4; ++r) {
          float pm = fmaxf(fmaxf(sa[mi][0][r], sa[mi][1][r]),
                           fmaxf(sa[mi][2][r], sa[mi][3][r]));
#pragma unroll
          for (int msk = 1; msk < 16; msk <<= 1)
            pm = fmaxf(pm, __shfl_xor(pm, msk));
          float mo = mrun[mi][r];
          float mn = fmaxf(mo, pm);
          alpha[mi][r] = __expf(mo - mn);
          mrun[mi][r] = mn;
        }
      float rs[2][4];
#pragma unroll
      for (int mi = 0; mi < 2; ++mi)
#pragma unroll
        for (int r = 0; r < 4; ++r) {
          float mn = mrun[mi][r];
          int row = mi * 16 + hi * 4 + r;
          int sw = (row & 7) << 3;
          float s2 = 0.f;
#pragma unroll
          for (int nj = 0; nj < 4; ++nj) {
            float p = __expf(sa[mi][nj][r] - mn);
            Ps[wave][row * 64 + ((nj * 16 + lo) ^ sw)] = f2bf(p);
            s2 += p;
          }
#pragma unroll
          for (int msk = 1; msk < 16; msk <<= 1)
            s2 += __shfl_xor(s2, msk);
          rs[mi][r] = s2;
        }
#pragma unroll
      for (int mi = 0; mi < 2; ++mi)
#pragma unroll
        for (int r = 0; r < 4; ++r)
          lrun[mi][r] = lrun[mi][r] * alpha[mi][r] + rs[mi][r];
#pragma unroll
      for (int mi = 0; mi < 2; ++mi)
#pragma unroll
        for (int dt = 0; dt < 8; ++dt)
#pragma unroll
          for (int r = 0; r < 4; ++r)
            acc_o[mi][dt][r] *= alpha[mi][r];
      // ---- PV: acc_o[mi][dt] += P[mi] x V ----
      __syncthreads();  // wave-local P is fine, but cheap barrier keeps LDS view sane
#pragma unroll
      for (int kk = 0; kk < 2; ++kk) {
        int prow0 = lo, prow1 = 16 + lo;
        bf16x8 ap0 = *(const bf16x8*)&Ps[wave][prow0 * 64 + ((kk * 32 + hi * 8) ^ ((prow0 & 7) << 3))];
        bf16x8 ap1 = *(const bf16x8*)&Ps[wave][prow1 * 64 + ((kk * 32 + hi * 8) ^ ((prow1 & 7) << 3))];
#pragma unroll
        for (int dt = 0; dt < 8; ++dt) {
          int row = dt * 16 + lo;
          bf16x8 bv = *(const bf16x8*)&Vs[bufc][row * 64 + ((kk * 4 + hi) ^ (row & 7)) * 8];
          acc_o[0][dt] = MFMA(ap0, bv, acc_o[0][dt]);
          acc_o[1][dt] = MFMA(ap1, bv, acc_o[1][dt]);
        }
      }
    } else {
      __syncthreads();  // keep barrier count uniform across waves
    }
    bufc ^= 1;
  }
#pragma unroll
  for (int mi = 0; mi < 2; ++mi)
#pragma unroll
    for (int r = 0; r < 4; ++r) {
      float iv = 1.f / lrun[mi][r];
      int q = qg0 + mi * 16 + hi * 4 + r;
      size_t rowbase = ((size_t)(b * T_ + q)) * (H_ * D_) + (size_t)h * D_;
#pragma unroll
      for (int dt = 0; dt < 8; ++dt)
        ab[rowbase + dt * 16 + lo] = f2bf(acc_o[mi][dt][r] * iv);
    }
}

// ---------------- launch ----------------

extern "C" void kernel_launch(void* const* d_in, const int* in_sizes, int n_in,
                              void* d_out, int out_size, void* d_ws, size_t ws_size,
                              hipStream_t stream) {
  const float* x  = (const float*)d_in[0];
  const float* Wq = (const float*)d_in[1];
  const float* Wk = (const float*)d_in[2];
  const float* Wv = (const float*)d_in[3];
  const float* Wo = (const float*)d_in[4];

  char* base = (char*)d_ws;
  size_t off = 0;
  auto nxt = [&](size_t bytes) {
    char* r = base + off;
    off += (bytes + 255) & ~(size_t)255;
    return r;
  };
  u16*   xb  = (u16*)nxt((size_t)BT_ * E_ * 2);
  u16*   wqT = (u16*)nxt((size_t)E_ * E_ * 2);          // [2048][2048]
  u16*   wkT = (u16*)nxt((size_t)(G_ * D_) * E_ * 2);   // [512][2048]
  u16*   wvT = (u16*)nxt((size_t)(G_ * D_) * E_ * 2);
  u16*   woT = (u16*)nxt((size_t)E_ * E_ * 2);
  float* ct  = (float*)nxt((size_t)T_ * 64 * 4);
  float* st  = (float*)nxt((size_t)T_ * 64 * 4);
  u16*   qg  = (u16*)nxt((size_t)BT_ * E_ * 2);
  u16*   kg  = (u16*)nxt((size_t)BT_ * (G_ * D_) * 2);
  u16*   vg  = (u16*)nxt((size_t)BT_ * (G_ * D_) * 2);
  u16*   vTb = (u16*)nxt((size_t)BT_ * (G_ * D_) * 2);
  // safe aliases (strict producer/consumer ordering):
  u16* qhb = xb;   // xb last read by v-GEMM; qhb written after
  u16* khb = wqT;  // wqT last read by q-GEMM; khb written after
  u16* ab  = qg;   // qg last read by k_rope(q); ab written by k_attn after

  k_cvt_x<<<BT_ * E_ / 4 / 256, 256, 0, stream>>>((const float4*)x, (uint2*)xb);
  k_cvt_wT<<<dim3(E_ / 64, E_ / 64), 256, 0, stream>>>(Wq, wqT, E_, E_);
  k_cvt_wT<<<dim3((G_ * D_) / 64, E_ / 64), 256, 0, stream>>>(Wk, wkT, E_, G_ * D_);
  k_cvt_wT<<<dim3((G_ * D_) / 64, E_ / 64), 256, 0, stream>>>(Wv, wvT, E_, G_ * D_);
  k_cvt_wT<<<dim3(E_ / 64, E_ / 64), 256, 0, stream>>>(Wo, woT, E_, E_);
  k_tables<<<T_ * 64 / 256, 256, 0, stream>>>(ct, st);

  k_gemm_bt<1><<<dim3(E_ / 128, BT_ / 128), 256, 0, stream>>>(xb, wqT, qg, BT_, E_, E_);
  k_gemm_bt<1><<<dim3((G_ * D_) / 128, BT_ / 128), 256, 0, stream>>>(xb, wkT, kg, BT_, G_ * D_, E_);
  k_gemm_bt<1><<<dim3((G_ * D_) / 128, BT_ / 128), 256, 0, stream>>>(xb, wvT, vg, BT_, G_ * D_, E_);

  k_rope<<<BT_ * H_ * 64 / 256, 256, 0, stream>>>(qg, qhb, ct, st, 4);
  k_rope<<<BT_ * G_ * 64 / 256, 256, 0, stream>>>(kg, khb, ct, st, 2);
  k_vtrans<<<dim3(T_ / 64, D_ / 64, B_ * G_), 256, 0, stream>>>(vg, vTb);

  k_attn<<<dim3(T_ / 128, B_ * H_), 256, 0, stream>>>(qhb, khb, vTb, ab);

  k_gemm_bt<0><<<dim3(E_ / 128, BT_ / 128), 256, 0, stream>>>(ab, woT, d_out, BT_, E_, E_);
}